// Round 2
// baseline (209.236 us; speedup 1.0000x reference)
//
#include <hip/hip_runtime.h>

#define TT 32
#define EMB 256
#define HEAD 64

typedef __attribute__((ext_vector_type(8)))  short    bf16x8;
typedef __attribute__((ext_vector_type(16))) float    f32x16;
typedef __attribute__((ext_vector_type(4)))  float    f32x4;
typedef __attribute__((ext_vector_type(4)))  unsigned uint4v;

__device__ __forceinline__ unsigned bfr(float f) {   // bf16 bits (RNE), low 16
  unsigned u = __builtin_bit_cast(unsigned, f);
  u += 0x7fffu + ((u >> 16) & 1u);
  return u >> 16;
}
__device__ __forceinline__ unsigned pk2(float a, float b) {  // lo=a, hi=b
  return bfr(a) | (bfr(b) << 16);
}
// permlane32_swap: x = {lo-half: a(own), hi-half: b(from lane-32)}
//                  y = {lo-half: a(from lane+32), hi-half: b(own)}
__device__ __forceinline__ void plswap(unsigned a, unsigned b,
                                       unsigned& x, unsigned& y) {
  auto r = __builtin_amdgcn_permlane32_swap(a, b, false, false);
  x = r[0]; y = r[1];
}

// Wt[n][k] = W_{n/64}[k][n%64] as bf16; n in [0,192), k in [0,256)
__global__ void prep_weights(const float* __restrict__ Wq,
                             const float* __restrict__ Wk,
                             const float* __restrict__ Wv,
                             unsigned short* __restrict__ Wt) {
  int idx = blockIdx.x * 256 + threadIdx.x;   // 192*256 total
  int n = idx >> 8, k = idx & 255;
  const float* W = (n < 64) ? Wq : (n < 128) ? Wk : Wv;
  Wt[n * 256 + k] = (unsigned short)bfr(W[k * 64 + (n & 63)]);
}

__global__ __launch_bounds__(256, 4)
void attn_kernel(const float* __restrict__ X,
                 const unsigned short* __restrict__ Wt,
                 const float* __restrict__ bq,
                 const float* __restrict__ bk,
                 const float* __restrict__ bv,
                 float* __restrict__ out) {
  const int tid  = threadIdx.x;
  const int lane = tid & 63;
  const int lo   = lane & 31;   // MFMA tile row/col
  const int hi   = lane >> 5;   // k-half selector
  const long b   = (long)blockIdx.x * 4 + (tid >> 6);

  const float* Xb = X + b * (TT * EMB);

  // ================= pass A: QT,KT = W^T · X^T =================
  // D[h][t]: lane holds col t=lo, rows h=(r&3)+8*(r>>2)+4*hi (+32*nt)
  f32x16 aQ[2], aK[2];
#pragma unroll
  for (int nt = 0; nt < 2; ++nt)
#pragma unroll
    for (int g = 0; g < 4; ++g) {
      // rows for (g, q=0..3) are consecutive: 8g+4hi .. +3  -> f32x4 bias load
      f32x4 tq = *(const f32x4*)(bq + nt * 32 + g * 8 + hi * 4);
      f32x4 tk = *(const f32x4*)(bk + nt * 32 + g * 8 + hi * 4);
#pragma unroll
      for (int q = 0; q < 4; ++q) {
        aQ[nt][g * 4 + q] = tq[q];
        aK[nt][g * 4 + q] = tk[q];
      }
    }

#pragma unroll
  for (int kk = 0; kk < 16; ++kk) {
    const float* xp = Xb + lo * EMB + kk * 16 + hi * 8;
    f32x4 x0 = *(const f32x4*)xp;
    f32x4 x1 = *(const f32x4*)(xp + 4);
    uint4v aw = { pk2(x0[0], x0[1]), pk2(x0[2], x0[3]),
                  pk2(x1[0], x1[1]), pk2(x1[2], x1[3]) };
    bf16x8 a = __builtin_bit_cast(bf16x8, aw);   // X[lo][kk*16+hi*8+j]
#pragma unroll
    for (int nt = 0; nt < 2; ++nt) {
      bf16x8 wq = *(const bf16x8*)(Wt + (nt * 32 + lo) * 256 + kk * 16 + hi * 8);
      aQ[nt] = __builtin_amdgcn_mfma_f32_32x32x16_bf16(wq, a, aQ[nt], 0, 0, 0);
      bf16x8 wk = *(const bf16x8*)(Wt + (64 + nt * 32 + lo) * 256 + kk * 16 + hi * 8);
      aK[nt] = __builtin_amdgcn_mfma_f32_32x32x16_bf16(wk, a, aK[nt], 0, 0, 0);
    }
  }

  // stash as packed bf16 pairs along q: [nt][g][pair]
  unsigned Qp[2][4][2], Kp[2][4][2];
#pragma unroll
  for (int nt = 0; nt < 2; ++nt)
#pragma unroll
    for (int g = 0; g < 4; ++g) {
      Qp[nt][g][0] = pk2(aQ[nt][g * 4 + 0], aQ[nt][g * 4 + 1]);
      Qp[nt][g][1] = pk2(aQ[nt][g * 4 + 2], aQ[nt][g * 4 + 3]);
      Kp[nt][g][0] = pk2(aK[nt][g * 4 + 0], aK[nt][g * 4 + 1]);
      Kp[nt][g][1] = pk2(aK[nt][g * 4 + 2], aK[nt][g * 4 + 3]);
    }

  // ================= pass B: V = X · Wv (normal) =================
  // D[t][h]: lane holds col h=lo (+32*nt), rows t
  const float* Xb2 = Xb;
  asm volatile("" : "+v"(Xb2));   // block load-CSE with pass A (X re-read hits L2)
  f32x16 aV[2];
  {
    float bv0 = bv[lo], bv1 = bv[32 + lo];
#pragma unroll
    for (int r = 0; r < 16; ++r) { aV[0][r] = bv0; aV[1][r] = bv1; }
  }
#pragma unroll
  for (int kk = 0; kk < 16; ++kk) {
    const float* xp = Xb2 + lo * EMB + kk * 16 + hi * 8;
    f32x4 x0 = *(const f32x4*)xp;
    f32x4 x1 = *(const f32x4*)(xp + 4);
    uint4v aw = { pk2(x0[0], x0[1]), pk2(x0[2], x0[3]),
                  pk2(x1[0], x1[1]), pk2(x1[2], x1[3]) };
    bf16x8 a = __builtin_bit_cast(bf16x8, aw);
#pragma unroll
    for (int nt = 0; nt < 2; ++nt) {
      bf16x8 wv = *(const bf16x8*)(Wt + (128 + nt * 32 + lo) * 256 + kk * 16 + hi * 8);
      aV[nt] = __builtin_amdgcn_mfma_f32_32x32x16_bf16(a, wv, aV[nt], 0, 0, 0);
    }
  }
  unsigned Vp[2][4][2];
#pragma unroll
  for (int nt = 0; nt < 2; ++nt)
#pragma unroll
    for (int g = 0; g < 4; ++g) {
      Vp[nt][g][0] = pk2(aV[nt][g * 4 + 0], aV[nt][g * 4 + 1]);
      Vp[nt][g][1] = pk2(aV[nt][g * 4 + 2], aV[nt][g * 4 + 3]);
    }

  // ================= QK^T (swapped): weiT = K · Q^T =================
  // fragment build: h-block m=2kk+hi; words from permlane32_swap of (g0,g1)
  f32x16 wei;
#pragma unroll
  for (int r = 0; r < 16; ++r) wei[r] = 0.0f;
#pragma unroll
  for (int kk = 0; kk < 4; ++kk) {
    const int nt = kk >> 1, g0 = (2 * kk) & 3, g1 = (2 * kk + 1) & 3;
    unsigned k0w, k1w, k2w, k3w, q0w, q1w, q2w, q3w;
    plswap(Kp[nt][g0][0], Kp[nt][g1][0], k0w, k2w);
    plswap(Kp[nt][g0][1], Kp[nt][g1][1], k1w, k3w);
    plswap(Qp[nt][g0][0], Qp[nt][g1][0], q0w, q2w);
    plswap(Qp[nt][g0][1], Qp[nt][g1][1], q1w, q3w);
    uint4v kw = { k0w, k1w, k2w, k3w };
    uint4v qw = { q0w, q1w, q2w, q3w };
    wei = __builtin_amdgcn_mfma_f32_32x32x16_bf16(
        __builtin_bit_cast(bf16x8, kw), __builtin_bit_cast(bf16x8, qw), wei, 0, 0, 0);
  }

  // ================= softmax over s for query t=lo (lane pairs l, l^32) ====
  float pv[16];
  float m = -3.0e38f;
#pragma unroll
  for (int r = 0; r < 16; ++r) {
    int s = (r & 3) + 8 * (r >> 2) + 4 * hi;
    float v = (s <= lo) ? wei[r] * 0.125f : -__builtin_inff();  // mask, /sqrt(64)
    pv[r] = v;
    m = fmaxf(m, v);
  }
  m = fmaxf(m, __shfl_xor(m, 32));
  float sum = 0.0f;
#pragma unroll
  for (int r = 0; r < 16; ++r) {
    float e = __expf(pv[r] - m);
    pv[r] = e;
    sum += e;
  }
  sum += __shfl_xor(sum, 32);
  const float inv = 1.0f / sum;

  unsigned Pp[4][2];
#pragma unroll
  for (int g = 0; g < 4; ++g) {
    Pp[g][0] = pk2(pv[g * 4 + 0] * inv, pv[g * 4 + 1] * inv);
    Pp[g][1] = pk2(pv[g * 4 + 2] * inv, pv[g * 4 + 3] * inv);
  }

  // ================= out = P · V =================
  f32x16 o[2];
#pragma unroll
  for (int i = 0; i < 2; ++i)
#pragma unroll
    for (int r = 0; r < 16; ++r) o[i][r] = 0.0f;

#pragma unroll
  for (int kk = 0; kk < 2; ++kk) {
    const int g0 = 2 * kk, g1 = 2 * kk + 1;
    unsigned p0w, p1w, p2w, p3w;
    plswap(Pp[g0][0], Pp[g1][0], p0w, p2w);
    plswap(Pp[g0][1], Pp[g1][1], p1w, p3w);
    uint4v pw = { p0w, p1w, p2w, p3w };
    bf16x8 pa = __builtin_bit_cast(bf16x8, pw);
#pragma unroll
    for (int nt = 0; nt < 2; ++nt) {
      unsigned v0w, v1w, v2w, v3w;
      plswap(Vp[nt][g0][0], Vp[nt][g1][0], v0w, v2w);
      plswap(Vp[nt][g0][1], Vp[nt][g1][1], v1w, v3w);
      uint4v vw = { v0w, v1w, v2w, v3w };
      o[nt] = __builtin_amdgcn_mfma_f32_32x32x16_bf16(
          pa, __builtin_bit_cast(bf16x8, vw), o[nt], 0, 0, 0);
    }
  }

  // coalesced fp32 stores (2×128B segments per instr)
  float* ob = out + b * (TT * HEAD);
#pragma unroll
  for (int nt = 0; nt < 2; ++nt) {
    int h = nt * 32 + lo;
#pragma unroll
    for (int r = 0; r < 16; ++r) {
      int row = (r & 3) + 8 * (r >> 2) + 4 * hi;
      ob[row * HEAD + h] = o[nt][r];
    }
  }
}

extern "C" void kernel_launch(void* const* d_in, const int* in_sizes, int n_in,
                              void* d_out, int out_size, void* d_ws, size_t ws_size,
                              hipStream_t stream) {
  const float* X  = (const float*)d_in[0];
  const float* Wq = (const float*)d_in[1];
  const float* bq = (const float*)d_in[2];
  const float* Wk = (const float*)d_in[3];
  const float* bk = (const float*)d_in[4];
  const float* Wv = (const float*)d_in[5];
  const float* bv = (const float*)d_in[6];
  float* out = (float*)d_out;
  unsigned short* Wt = (unsigned short*)d_ws;  // 192*256 bf16 = 96 KB scratch

  const int B = in_sizes[0] / (TT * EMB);  // 8192

  prep_weights<<<192, 256, 0, stream>>>(Wq, Wk, Wv, Wt);
  attn_kernel<<<B / 4, 256, 0, stream>>>(X, Wt, bq, bk, bv, out);
}

// Round 3
// 148.787 us; speedup vs baseline: 1.4063x; 1.4063x over previous
//
#include <hip/hip_runtime.h>

#define TT 32
#define EMB 256
#define HEAD 64

typedef __attribute__((ext_vector_type(8)))  short    bf16x8;
typedef __attribute__((ext_vector_type(16))) float    f32x16;
typedef __attribute__((ext_vector_type(4)))  float    f32x4;
typedef __attribute__((ext_vector_type(4)))  unsigned uint4v;

__device__ __forceinline__ unsigned bfr(float f) {   // bf16 bits (RNE), low 16
  unsigned u = __builtin_bit_cast(unsigned, f);
  u += 0x7fffu + ((u >> 16) & 1u);
  return u >> 16;
}
__device__ __forceinline__ unsigned pk2(float a, float b) {  // lo=a, hi=b
  return bfr(a) | (bfr(b) << 16);
}
__device__ __forceinline__ void plswap(unsigned a, unsigned b,
                                       unsigned& x, unsigned& y) {
  auto r = __builtin_amdgcn_permlane32_swap(a, b, false, false);
  x = r[0]; y = r[1];
}

// Wt[n][k] = W_{n/64}[k][n%64] as bf16; n in [0,192), k in [0,256)
__global__ void prep_weights(const float* __restrict__ Wq,
                             const float* __restrict__ Wk,
                             const float* __restrict__ Wv,
                             unsigned short* __restrict__ Wt) {
  int idx = blockIdx.x * 256 + threadIdx.x;   // 192*256 total
  int n = idx >> 8, k = idx & 255;
  const float* W = (n < 64) ? Wq : (n < 128) ? Wk : Wv;
  Wt[n * 256 + k] = (unsigned short)bfr(W[k * 64 + (n & 63)]);
}

// one wave per batch item; X tile staged fp32 in LDS via global_load_lds.
// LDS layout: 16 panels (one per k-step) of [32 rows][16 floats],
// swizzled within row: float_col' = col ^ ((row&3)<<2)  (i.e. byte ^ (row&3)<<4)
__global__ __launch_bounds__(64, 2)
void attn_kernel(const float* __restrict__ X,
                 const unsigned short* __restrict__ Wt,
                 const float* __restrict__ bq,
                 const float* __restrict__ bk,
                 const float* __restrict__ bv,
                 float* __restrict__ out) {
  __shared__ __align__(16) float sX[8192];   // 32 KB

  const int lane = threadIdx.x;   // block = 1 wave
  const int lo   = lane & 31;     // MFMA tile row/col
  const int hi   = lane >> 5;     // k-half selector
  const long b   = blockIdx.x;

  const float* Xb = X + b * (TT * EMB);

  // ---------------- DMA: X tile -> LDS (32 x 1KB instructions) -------------
  // instr i: panel p=i>>1, row-half h=i&1 (rows h*16..h*16+15), lane l writes
  // LDS linear (i*1024 + l*16). Inverse-swizzled global source:
  //   row = h*16 + (l>>2);  colf = p*16 + (((l&3)<<2) ^ (((l>>2)&3)<<2))
  {
    const int r4 = lane >> 2;                                  // 0..15
    const int cf = ((lane & 3) << 2) ^ ((r4 & 3) << 2);
    const float* base0 = Xb + r4 * 256 + cf;
#pragma unroll
    for (int i = 0; i < 32; ++i) {
      const float* src = base0 + (i & 1) * 4096 + (i >> 1) * 16;
      __builtin_amdgcn_global_load_lds(
          (const __attribute__((address_space(1))) void*)src,
          (__attribute__((address_space(3))) void*)(&sX[i * 256]),
          16, 0, 0);
    }
  }

  // ---------------- acc init with bias ----------------
  // QT/KT tiles: D[h][t], lane holds col t=lo, rows h=(r&3)+8*(r>>2)+4*hi+32nt
  f32x16 aQ[2], aK[2], aV[2];
#pragma unroll
  for (int nt = 0; nt < 2; ++nt)
#pragma unroll
    for (int g = 0; g < 4; ++g) {
      f32x4 tq = *(const f32x4*)(bq + nt * 32 + g * 8 + hi * 4);
      f32x4 tk = *(const f32x4*)(bk + nt * 32 + g * 8 + hi * 4);
#pragma unroll
      for (int q = 0; q < 4; ++q) {
        aQ[nt][g * 4 + q] = tq[q];
        aK[nt][g * 4 + q] = tk[q];
      }
    }
  {
    float bv0 = bv[lo], bv1 = bv[32 + lo];
#pragma unroll
    for (int r = 0; r < 16; ++r) { aV[0][r] = bv0; aV[1][r] = bv1; }
  }

  // wait for the DMA, fence any reordering of the LDS reads
  asm volatile("s_waitcnt vmcnt(0)" ::: "memory");
  __builtin_amdgcn_sched_barrier(0);

  // ---------------- merged projection: QT,KT = W^T·X^T ; V = X·Wv ----------
#pragma unroll
  for (int kk = 0; kk < 16; ++kk) {
    const int fb = kk * 512 + lo * 16;          // panel base + row base (floats)
    const int sw = (lo & 3) << 2;
    f32x4 x0 = *(const f32x4*)(sX + fb + ((hi * 8 + 0) ^ sw));
    f32x4 x1 = *(const f32x4*)(sX + fb + ((hi * 8 + 4) ^ sw));
    uint4v aw = { pk2(x0[0], x0[1]), pk2(x0[2], x0[3]),
                  pk2(x1[0], x1[1]), pk2(x1[2], x1[3]) };
    bf16x8 a = __builtin_bit_cast(bf16x8, aw);  // X[lo][kk*16+hi*8+j]
#pragma unroll
    for (int nt = 0; nt < 2; ++nt) {
      bf16x8 wq = *(const bf16x8*)(Wt + (nt * 32 + lo) * 256 + kk * 16 + hi * 8);
      aQ[nt] = __builtin_amdgcn_mfma_f32_32x32x16_bf16(wq, a, aQ[nt], 0, 0, 0);
      bf16x8 wk = *(const bf16x8*)(Wt + (64 + nt * 32 + lo) * 256 + kk * 16 + hi * 8);
      aK[nt] = __builtin_amdgcn_mfma_f32_32x32x16_bf16(wk, a, aK[nt], 0, 0, 0);
      bf16x8 wv = *(const bf16x8*)(Wt + (128 + nt * 32 + lo) * 256 + kk * 16 + hi * 8);
      aV[nt] = __builtin_amdgcn_mfma_f32_32x32x16_bf16(a, wv, aV[nt], 0, 0, 0);
    }
  }

  // pack as bf16 pairs along q: [nt][g][pair]
  unsigned Qp[2][4][2], Kp[2][4][2], Vp[2][4][2];
#pragma unroll
  for (int nt = 0; nt < 2; ++nt)
#pragma unroll
    for (int g = 0; g < 4; ++g) {
      Qp[nt][g][0] = pk2(aQ[nt][g * 4 + 0], aQ[nt][g * 4 + 1]);
      Qp[nt][g][1] = pk2(aQ[nt][g * 4 + 2], aQ[nt][g * 4 + 3]);
      Kp[nt][g][0] = pk2(aK[nt][g * 4 + 0], aK[nt][g * 4 + 1]);
      Kp[nt][g][1] = pk2(aK[nt][g * 4 + 2], aK[nt][g * 4 + 3]);
      Vp[nt][g][0] = pk2(aV[nt][g * 4 + 0], aV[nt][g * 4 + 1]);
      Vp[nt][g][1] = pk2(aV[nt][g * 4 + 2], aV[nt][g * 4 + 3]);
    }

  // ---------------- QK^T (swapped): weiT = K · Q^T ----------------
  f32x16 wei;
#pragma unroll
  for (int r = 0; r < 16; ++r) wei[r] = 0.0f;
#pragma unroll
  for (int kk = 0; kk < 4; ++kk) {
    const int nt = kk >> 1, g0 = (2 * kk) & 3, g1 = (2 * kk + 1) & 3;
    unsigned k0w, k1w, k2w, k3w, q0w, q1w, q2w, q3w;
    plswap(Kp[nt][g0][0], Kp[nt][g1][0], k0w, k2w);
    plswap(Kp[nt][g0][1], Kp[nt][g1][1], k1w, k3w);
    plswap(Qp[nt][g0][0], Qp[nt][g1][0], q0w, q2w);
    plswap(Qp[nt][g0][1], Qp[nt][g1][1], q1w, q3w);
    uint4v kw = { k0w, k1w, k2w, k3w };
    uint4v qw = { q0w, q1w, q2w, q3w };
    wei = __builtin_amdgcn_mfma_f32_32x32x16_bf16(
        __builtin_bit_cast(bf16x8, kw), __builtin_bit_cast(bf16x8, qw), wei, 0, 0, 0);
  }

  // ---------------- softmax over s for query t=lo (lane pairs l, l^32) -----
  float pv[16];
  float m = -3.0e38f;
#pragma unroll
  for (int r = 0; r < 16; ++r) {
    int s = (r & 3) + 8 * (r >> 2) + 4 * hi;
    float v = (s <= lo) ? wei[r] * 0.125f : -__builtin_inff();
    pv[r] = v;
    m = fmaxf(m, v);
  }
  m = fmaxf(m, __shfl_xor(m, 32));
  float sum = 0.0f;
#pragma unroll
  for (int r = 0; r < 16; ++r) {
    float e = __expf(pv[r] - m);
    pv[r] = e;
    sum += e;
  }
  sum += __shfl_xor(sum, 32);
  const float inv = 1.0f / sum;

  unsigned Pp[4][2];
#pragma unroll
  for (int g = 0; g < 4; ++g) {
    Pp[g][0] = pk2(pv[g * 4 + 0] * inv, pv[g * 4 + 1] * inv);
    Pp[g][1] = pk2(pv[g * 4 + 2] * inv, pv[g * 4 + 3] * inv);
  }

  // ---------------- out = P · V ----------------
  f32x16 o[2];
#pragma unroll
  for (int i = 0; i < 2; ++i)
#pragma unroll
    for (int r = 0; r < 16; ++r) o[i][r] = 0.0f;

#pragma unroll
  for (int kk = 0; kk < 2; ++kk) {
    const int g0 = 2 * kk, g1 = 2 * kk + 1;
    unsigned p0w, p1w, p2w, p3w;
    plswap(Pp[g0][0], Pp[g1][0], p0w, p2w);
    plswap(Pp[g0][1], Pp[g1][1], p1w, p3w);
    uint4v pw = { p0w, p1w, p2w, p3w };
    bf16x8 pa = __builtin_bit_cast(bf16x8, pw);
#pragma unroll
    for (int nt = 0; nt < 2; ++nt) {
      unsigned v0w, v1w, v2w, v3w;
      plswap(Vp[nt][g0][0], Vp[nt][g1][0], v0w, v2w);
      plswap(Vp[nt][g0][1], Vp[nt][g1][1], v1w, v3w);
      uint4v vw = { v0w, v1w, v2w, v3w };
      o[nt] = __builtin_amdgcn_mfma_f32_32x32x16_bf16(
          pa, __builtin_bit_cast(bf16x8, vw), o[nt], 0, 0, 0);
    }
  }

  // coalesced fp32 stores (2×128B segments per instr)
  float* ob = out + b * (TT * HEAD);
#pragma unroll
  for (int nt = 0; nt < 2; ++nt) {
    int h = nt * 32 + lo;
#pragma unroll
    for (int r = 0; r < 16; ++r) {
      int row = (r & 3) + 8 * (r >> 2) + 4 * hi;
      ob[row * HEAD + h] = o[nt][r];
    }
  }
}

extern "C" void kernel_launch(void* const* d_in, const int* in_sizes, int n_in,
                              void* d_out, int out_size, void* d_ws, size_t ws_size,
                              hipStream_t stream) {
  const float* X  = (const float*)d_in[0];
  const float* Wq = (const float*)d_in[1];
  const float* bq = (const float*)d_in[2];
  const float* Wk = (const float*)d_in[3];
  const float* bk = (const float*)d_in[4];
  const float* Wv = (const float*)d_in[5];
  const float* bv = (const float*)d_in[6];
  float* out = (float*)d_out;
  unsigned short* Wt = (unsigned short*)d_ws;  // 192*256 bf16 = 96 KB scratch

  const int B = in_sizes[0] / (TT * EMB);  // 8192

  prep_weights<<<192, 256, 0, stream>>>(Wq, Wk, Wv, Wt);
  attn_kernel<<<B, 64, 0, stream>>>(X, Wt, bq, bk, bv, out);
}

// Round 4
// 87.163 us; speedup vs baseline: 2.4005x; 1.7070x over previous
//
#include <hip/hip_runtime.h>

#define TT 32
#define EMB 256
#define HEAD 64
#define NI 4   // items per wave

typedef __attribute__((ext_vector_type(8)))  short    bf16x8;
typedef __attribute__((ext_vector_type(16))) float    f32x16;
typedef __attribute__((ext_vector_type(4)))  float    f32x4;
typedef __attribute__((ext_vector_type(4)))  unsigned uint4v;

__device__ __forceinline__ unsigned bfr(float f) {   // bf16 bits (RNE), low 16
  unsigned u = __builtin_bit_cast(unsigned, f);
  u += 0x7fffu + ((u >> 16) & 1u);
  return u >> 16;
}
__device__ __forceinline__ unsigned pk2(float a, float b) {  // lo=a, hi=b
  unsigned r;
  asm("v_cvt_pk_bf16_f32 %0, %1, %2" : "=v"(r) : "v"(a), "v"(b));
  return r;
}
__device__ __forceinline__ void plswap(unsigned a, unsigned b,
                                       unsigned& x, unsigned& y) {
  auto r = __builtin_amdgcn_permlane32_swap(a, b, false, false);
  x = r[0]; y = r[1];
}

// Wt[n][k] = W_{n/64}[k][n%64] bf16, stored SWIZZLED: u16 idx = n*256 + (k ^ ((n&7)<<3))
__global__ void prep_weights(const float* __restrict__ Wq,
                             const float* __restrict__ Wk,
                             const float* __restrict__ Wv,
                             unsigned short* __restrict__ Wt) {
  int idx = blockIdx.x * 256 + threadIdx.x;   // 192*256 total
  int n = idx >> 8, k = idx & 255;
  const float* W = (n < 64) ? Wq : (n < 128) ? Wk : Wv;
  Wt[n * 256 + (k ^ ((n & 7) << 3))] = (unsigned short)bfr(W[k * 64 + (n & 63)]);
}

// block = 4 waves; Wt staged once in LDS (96 KB); each wave computes NI items,
// X pipelined one item ahead in VGPRs (T14 + counted vmcnt).
__global__ __launch_bounds__(256, 1)
void attn_kernel(const float* __restrict__ X,
                 const unsigned short* __restrict__ Wt,
                 const float* __restrict__ bq,
                 const float* __restrict__ bv,
                 float* __restrict__ out) {
  __shared__ unsigned short sW[192 * 256];   // 96 KB, swizzled layout

  const int tid  = threadIdx.x;
  const int wid  = tid >> 6;
  const int lane = tid & 63;
  const int lo   = lane & 31;   // MFMA tile row/col
  const int hi   = lane >> 5;   // k-half selector

  // ---- stage Wt -> LDS: linear 24 KB per wave (layout pre-swizzled) ----
  {
    const unsigned short* src = Wt + wid * 12288 + lane * 8;
#pragma unroll
    for (int i = 0; i < 24; ++i) {
      __builtin_amdgcn_global_load_lds(
          (const __attribute__((address_space(1))) void*)(src + i * 512),
          (__attribute__((address_space(3))) void*)(&sW[wid * 12288 + i * 512]),
          16, 0, 0);
    }
  }

  const long itemBase = (long)blockIdx.x * (4 * NI) + wid * NI;
  const float* Xb0 = X + itemBase * (TT * EMB);
  float* ob0 = out + itemBase * (TT * HEAD);

  // ---- loop-invariant bias regs ----
  // bq as Q-acc init (C layout: col t=lo, row h=(r&3)+8*(r>>2)+4*hi+32nt)
  f32x16 bQ2[2];
#pragma unroll
  for (int nt = 0; nt < 2; ++nt)
#pragma unroll
    for (int g = 0; g < 4; ++g) {
      f32x4 t = *(const f32x4*)(bq + nt * 32 + g * 8 + hi * 4);
#pragma unroll
      for (int q = 0; q < 4; ++q) bQ2[nt][g * 4 + q] = t[q];
    }
  // bv folds into PV accumulator init (softmax rows sum to 1); bk cancels.
  const float bv0 = bv[lo], bv1 = bv[32 + lo];

  // ---- prologue: issue item-0 X loads (32 x dwordx4, held in F) ----
  f32x4 F[32];
  {
    const float* Xp = Xb0 + lo * EMB + hi * 8;
#pragma unroll
    for (int i = 0; i < 32; ++i)
      F[i] = *(const f32x4*)(Xp + (i >> 1) * 16 + (i & 1) * 4);
  }

  __syncthreads();   // drains vmcnt(0)+lgkmcnt(0): sW and F[item0] both ready

#pragma unroll
  for (int j = 0; j < NI; ++j) {
    if (j > 0) {
      // outstanding = loads(j) [32, oldest] + stores(j-1) [32, newer];
      // in-order retirement => <=32 outstanding <=> loads(j) complete.
      asm volatile("s_waitcnt vmcnt(32)" ::: "memory");
    }
    __builtin_amdgcn_sched_barrier(0);

    // ---- cvt F -> bf16 fragments for item j ----
    uint4v Bf[16];
#pragma unroll
    for (int kk = 0; kk < 16; ++kk) {
      Bf[kk][0] = pk2(F[kk * 2][0],     F[kk * 2][1]);
      Bf[kk][1] = pk2(F[kk * 2][2],     F[kk * 2][3]);
      Bf[kk][2] = pk2(F[kk * 2 + 1][0], F[kk * 2 + 1][1]);
      Bf[kk][3] = pk2(F[kk * 2 + 1][2], F[kk * 2 + 1][3]);
    }
    __builtin_amdgcn_sched_barrier(0);

    // ---- issue item j+1 X loads (overlap with this item's compute) ----
    if (j + 1 < NI) {
      const float* Xp = Xb0 + (j + 1) * (TT * EMB) + lo * EMB + hi * 8;
#pragma unroll
      for (int i = 0; i < 32; ++i)
        F[i] = *(const f32x4*)(Xp + (i >> 1) * 16 + (i & 1) * 4);
    }
    __builtin_amdgcn_sched_barrier(0);

    // ---- projection: QT,KT = W^T·X^T ; V = X·Wv  (weights from LDS) ----
    f32x16 aQ[2], aK[2], aV[2];
    aQ[0] = bQ2[0]; aQ[1] = bQ2[1];
#pragma unroll
    for (int nt = 0; nt < 2; ++nt)
#pragma unroll
      for (int r = 0; r < 16; ++r) { aK[nt][r] = 0.0f; aV[nt][r] = 0.0f; }

#pragma unroll
    for (int kk = 0; kk < 16; ++kk) {
      bf16x8 a = __builtin_bit_cast(bf16x8, Bf[kk]);
      const int csw = (kk * 16 + hi * 8) ^ ((lo & 7) << 3);  // swizzled u16 col
#pragma unroll
      for (int nt = 0; nt < 2; ++nt) {
        bf16x8 wq = *(const bf16x8*)&sW[(nt * 32 + lo) * 256 + csw];
        aQ[nt] = __builtin_amdgcn_mfma_f32_32x32x16_bf16(wq, a, aQ[nt], 0, 0, 0);
        bf16x8 wk = *(const bf16x8*)&sW[(64 + nt * 32 + lo) * 256 + csw];
        aK[nt] = __builtin_amdgcn_mfma_f32_32x32x16_bf16(wk, a, aK[nt], 0, 0, 0);
        bf16x8 wv = *(const bf16x8*)&sW[(128 + nt * 32 + lo) * 256 + csw];
        aV[nt] = __builtin_amdgcn_mfma_f32_32x32x16_bf16(a, wv, aV[nt], 0, 0, 0);
      }
    }

    // ---- pack as bf16 pairs along q: [nt][g][pair] ----
    unsigned Qp[2][4][2], Kp[2][4][2], Vp[2][4][2];
#pragma unroll
    for (int nt = 0; nt < 2; ++nt)
#pragma unroll
      for (int g = 0; g < 4; ++g) {
        Qp[nt][g][0] = pk2(aQ[nt][g * 4 + 0], aQ[nt][g * 4 + 1]);
        Qp[nt][g][1] = pk2(aQ[nt][g * 4 + 2], aQ[nt][g * 4 + 3]);
        Kp[nt][g][0] = pk2(aK[nt][g * 4 + 0], aK[nt][g * 4 + 1]);
        Kp[nt][g][1] = pk2(aK[nt][g * 4 + 2], aK[nt][g * 4 + 3]);
        Vp[nt][g][0] = pk2(aV[nt][g * 4 + 0], aV[nt][g * 4 + 1]);
        Vp[nt][g][1] = pk2(aV[nt][g * 4 + 2], aV[nt][g * 4 + 3]);
      }

    // ---- QK^T (swapped): weiT = K · Q^T ----
    f32x16 wei;
#pragma unroll
    for (int r = 0; r < 16; ++r) wei[r] = 0.0f;
#pragma unroll
    for (int kk = 0; kk < 4; ++kk) {
      const int nt = kk >> 1, g0 = (2 * kk) & 3, g1 = (2 * kk + 1) & 3;
      unsigned k0w, k1w, k2w, k3w, q0w, q1w, q2w, q3w;
      plswap(Kp[nt][g0][0], Kp[nt][g1][0], k0w, k2w);
      plswap(Kp[nt][g0][1], Kp[nt][g1][1], k1w, k3w);
      plswap(Qp[nt][g0][0], Qp[nt][g1][0], q0w, q2w);
      plswap(Qp[nt][g0][1], Qp[nt][g1][1], q1w, q3w);
      uint4v kw = { k0w, k1w, k2w, k3w };
      uint4v qw = { q0w, q1w, q2w, q3w };
      wei = __builtin_amdgcn_mfma_f32_32x32x16_bf16(
          __builtin_bit_cast(bf16x8, kw), __builtin_bit_cast(bf16x8, qw), wei, 0, 0, 0);
    }

    // ---- softmax over s for query t=lo (lane pairs l, l^32) ----
    float pv[16];
    float m = -3.0e38f;
#pragma unroll
    for (int r = 0; r < 16; ++r) {
      int s = (r & 3) + 8 * (r >> 2) + 4 * hi;
      float v = (s <= lo) ? wei[r] * 0.125f : -__builtin_inff();
      pv[r] = v;
      m = fmaxf(m, v);
    }
    m = fmaxf(m, __shfl_xor(m, 32));
    float sum = 0.0f;
#pragma unroll
    for (int r = 0; r < 16; ++r) {
      float e = __expf(pv[r] - m);
      pv[r] = e;
      sum += e;
    }
    sum += __shfl_xor(sum, 32);
    const float inv = 1.0f / sum;

    unsigned Pp[4][2];
#pragma unroll
    for (int g = 0; g < 4; ++g) {
      Pp[g][0] = pk2(pv[g * 4 + 0] * inv, pv[g * 4 + 1] * inv);
      Pp[g][1] = pk2(pv[g * 4 + 2] * inv, pv[g * 4 + 3] * inv);
    }

    // ---- out = P · V  (+ bv via acc init; softmax row-sum = 1) ----
    f32x16 o[2];
#pragma unroll
    for (int r = 0; r < 16; ++r) { o[0][r] = bv0; o[1][r] = bv1; }

#pragma unroll
    for (int kk = 0; kk < 2; ++kk) {
      const int g0 = 2 * kk, g1 = 2 * kk + 1;
      unsigned p0w, p1w, p2w, p3w;
      plswap(Pp[g0][0], Pp[g1][0], p0w, p2w);
      plswap(Pp[g0][1], Pp[g1][1], p1w, p3w);
      uint4v pw = { p0w, p1w, p2w, p3w };
      bf16x8 pa = __builtin_bit_cast(bf16x8, pw);
#pragma unroll
      for (int nt = 0; nt < 2; ++nt) {
        unsigned v0w, v1w, v2w, v3w;
        plswap(Vp[nt][g0][0], Vp[nt][g1][0], v0w, v2w);
        plswap(Vp[nt][g0][1], Vp[nt][g1][1], v1w, v3w);
        uint4v vw = { v0w, v1w, v2w, v3w };
        o[nt] = __builtin_amdgcn_mfma_f32_32x32x16_bf16(
            pa, __builtin_bit_cast(bf16x8, vw), o[nt], 0, 0, 0);
      }
    }

    // ---- stores (32 x dword, 2x128B segments each) ----
    float* ob = ob0 + j * (TT * HEAD);
#pragma unroll
    for (int nt = 0; nt < 2; ++nt) {
      int h = nt * 32 + lo;
#pragma unroll
      for (int r = 0; r < 16; ++r) {
        int row = (r & 3) + 8 * (r >> 2) + 4 * hi;
        ob[row * HEAD + h] = o[nt][r];
      }
    }
  }
}

extern "C" void kernel_launch(void* const* d_in, const int* in_sizes, int n_in,
                              void* d_out, int out_size, void* d_ws, size_t ws_size,
                              hipStream_t stream) {
  const float* X  = (const float*)d_in[0];
  const float* Wq = (const float*)d_in[1];
  const float* bq = (const float*)d_in[2];
  const float* Wk = (const float*)d_in[3];
  const float* bv = (const float*)d_in[6];
  const float* Wv = (const float*)d_in[5];
  float* out = (float*)d_out;
  unsigned short* Wt = (unsigned short*)d_ws;  // 192*256 bf16 = 96 KB scratch

  const int B = in_sizes[0] / (TT * EMB);  // 8192

  prep_weights<<<192, 256, 0, stream>>>(Wq, Wk, Wv, Wt);
  attn_kernel<<<B / (4 * NI), 256, 0, stream>>>(X, Wt, bq, bv, out);
}

// Round 5
// 79.181 us; speedup vs baseline: 2.6425x; 1.1008x over previous
//
#include <hip/hip_runtime.h>

#define TT 32
#define EMB 256
#define HEAD 64
#define NI 8   // items per wave; grid = 8192/(4*NI) = 256 = one block per CU

typedef __attribute__((ext_vector_type(8)))  short    bf16x8;
typedef __attribute__((ext_vector_type(16))) float    f32x16;
typedef __attribute__((ext_vector_type(4)))  float    f32x4;
typedef __attribute__((ext_vector_type(4)))  unsigned uint4v;

__device__ __forceinline__ unsigned bfr(float f) {   // bf16 bits (RNE), low 16
  unsigned u = __builtin_bit_cast(unsigned, f);
  u += 0x7fffu + ((u >> 16) & 1u);
  return u >> 16;
}
__device__ __forceinline__ unsigned pk2(float a, float b) {  // lo=a, hi=b
  unsigned r;
  asm("v_cvt_pk_bf16_f32 %0, %1, %2" : "=v"(r) : "v"(a), "v"(b));
  return r;
}
__device__ __forceinline__ void plswap(unsigned a, unsigned b,
                                       unsigned& x, unsigned& y) {
  auto r = __builtin_amdgcn_permlane32_swap(a, b, false, false);
  x = r[0]; y = r[1];
}

// Wt[n][k] = W_{n/64}[k][n%64] bf16, stored SWIZZLED: u16 idx = n*256 + (k ^ ((n&7)<<3))
__global__ void prep_weights(const float* __restrict__ Wq,
                             const float* __restrict__ Wk,
                             const float* __restrict__ Wv,
                             unsigned short* __restrict__ Wt) {
  int idx = blockIdx.x * 256 + threadIdx.x;   // 192*256 total
  int n = idx >> 8, k = idx & 255;
  const float* W = (n < 64) ? Wq : (n < 128) ? Wk : Wv;
  Wt[n * 256 + (k ^ ((n & 7) << 3))] = (unsigned short)bfr(W[k * 64 + (n & 63)]);
}

// block = 4 waves; Wt staged once in LDS (96 KB); each wave computes NI items,
// X pipelined one item ahead in VGPRs (T14 + counted vmcnt). One block per CU.
__global__ __launch_bounds__(256, 1)
void attn_kernel(const float* __restrict__ X,
                 const unsigned short* __restrict__ Wt,
                 const float* __restrict__ bq,
                 const float* __restrict__ bv,
                 float* __restrict__ out) {
  __shared__ unsigned short sW[192 * 256];   // 96 KB, swizzled layout

  const int tid  = threadIdx.x;
  const int wid  = tid >> 6;
  const int lane = tid & 63;
  const int lo   = lane & 31;   // MFMA tile row/col
  const int hi   = lane >> 5;   // k-half selector

  // ---- stage Wt -> LDS: linear 24 KB per wave (layout pre-swizzled) ----
  {
    const unsigned short* src = Wt + wid * 12288 + lane * 8;
#pragma unroll
    for (int i = 0; i < 24; ++i) {
      __builtin_amdgcn_global_load_lds(
          (const __attribute__((address_space(1))) void*)(src + i * 512),
          (__attribute__((address_space(3))) void*)(&sW[wid * 12288 + i * 512]),
          16, 0, 0);
    }
  }

  const long itemBase = (long)blockIdx.x * (4 * NI) + wid * NI;
  const float* Xb0 = X + itemBase * (TT * EMB);
  float* ob0 = out + itemBase * (TT * HEAD);

  // ---- loop-invariant bias regs ----
  // bq as Q-acc init (C layout: col t=lo, row h=(r&3)+8*(r>>2)+4*hi+32nt)
  f32x16 bQ2[2];
#pragma unroll
  for (int nt = 0; nt < 2; ++nt)
#pragma unroll
    for (int g = 0; g < 4; ++g) {
      f32x4 t = *(const f32x4*)(bq + nt * 32 + g * 8 + hi * 4);
#pragma unroll
      for (int q = 0; q < 4; ++q) bQ2[nt][g * 4 + q] = t[q];
    }
  // bv folds into PV accumulator init (softmax rows sum to 1); bk cancels.
  const float bv0 = bv[lo], bv1 = bv[32 + lo];

  // ---- prologue: issue item-0 X loads (32 x dwordx4, held in F) ----
  f32x4 F[32];
  {
    const float* Xp = Xb0 + lo * EMB + hi * 8;
#pragma unroll
    for (int i = 0; i < 32; ++i)
      F[i] = *(const f32x4*)(Xp + (i >> 1) * 16 + (i & 1) * 4);
  }

  __syncthreads();   // drains vmcnt+lgkmcnt: sW and F[item0] both ready

#pragma unroll 1
  for (int j = 0; j < NI; ++j) {
    // outstanding = loads(j) [32, oldest] + stores(j-1) [32, newer];
    // in-order retirement => <=32 outstanding <=> loads(j) complete. (j=0: no-op)
    asm volatile("s_waitcnt vmcnt(32)" ::: "memory");
    __builtin_amdgcn_sched_barrier(0);

    // ---- cvt F -> bf16 fragments for item j ----
    uint4v Bf[16];
#pragma unroll
    for (int kk = 0; kk < 16; ++kk) {
      Bf[kk][0] = pk2(F[kk * 2][0],     F[kk * 2][1]);
      Bf[kk][1] = pk2(F[kk * 2][2],     F[kk * 2][3]);
      Bf[kk][2] = pk2(F[kk * 2 + 1][0], F[kk * 2 + 1][1]);
      Bf[kk][3] = pk2(F[kk * 2 + 1][2], F[kk * 2 + 1][3]);
    }
    __builtin_amdgcn_sched_barrier(0);

    // ---- issue item j+1 X loads (overlap with this item's compute) ----
    if (j + 1 < NI) {
      const float* Xp = Xb0 + (j + 1) * (TT * EMB) + lo * EMB + hi * 8;
#pragma unroll
      for (int i = 0; i < 32; ++i)
        F[i] = *(const f32x4*)(Xp + (i >> 1) * 16 + (i & 1) * 4);
    }
    __builtin_amdgcn_sched_barrier(0);

    // ---- projection: QT,KT = W^T·X^T ; V = X·Wv  (weights from LDS) ----
    f32x16 aQ[2], aK[2], aV[2];
    aQ[0] = bQ2[0]; aQ[1] = bQ2[1];
#pragma unroll
    for (int nt = 0; nt < 2; ++nt)
#pragma unroll
      for (int r = 0; r < 16; ++r) { aK[nt][r] = 0.0f; aV[nt][r] = 0.0f; }

#pragma unroll
    for (int kk = 0; kk < 16; ++kk) {
      bf16x8 a = __builtin_bit_cast(bf16x8, Bf[kk]);
      const int csw = (kk * 16 + hi * 8) ^ ((lo & 7) << 3);  // swizzled u16 col
#pragma unroll
      for (int nt = 0; nt < 2; ++nt) {
        bf16x8 wq = *(const bf16x8*)&sW[(nt * 32 + lo) * 256 + csw];
        aQ[nt] = __builtin_amdgcn_mfma_f32_32x32x16_bf16(wq, a, aQ[nt], 0, 0, 0);
        bf16x8 wk = *(const bf16x8*)&sW[(64 + nt * 32 + lo) * 256 + csw];
        aK[nt] = __builtin_amdgcn_mfma_f32_32x32x16_bf16(wk, a, aK[nt], 0, 0, 0);
        bf16x8 wv = *(const bf16x8*)&sW[(128 + nt * 32 + lo) * 256 + csw];
        aV[nt] = __builtin_amdgcn_mfma_f32_32x32x16_bf16(a, wv, aV[nt], 0, 0, 0);
      }
    }

    // ---- pack as bf16 pairs along q: [nt][g][pair] ----
    unsigned Qp[2][4][2], Kp[2][4][2], Vp[2][4][2];
#pragma unroll
    for (int nt = 0; nt < 2; ++nt)
#pragma unroll
      for (int g = 0; g < 4; ++g) {
        Qp[nt][g][0] = pk2(aQ[nt][g * 4 + 0], aQ[nt][g * 4 + 1]);
        Qp[nt][g][1] = pk2(aQ[nt][g * 4 + 2], aQ[nt][g * 4 + 3]);
        Kp[nt][g][0] = pk2(aK[nt][g * 4 + 0], aK[nt][g * 4 + 1]);
        Kp[nt][g][1] = pk2(aK[nt][g * 4 + 2], aK[nt][g * 4 + 3]);
        Vp[nt][g][0] = pk2(aV[nt][g * 4 + 0], aV[nt][g * 4 + 1]);
        Vp[nt][g][1] = pk2(aV[nt][g * 4 + 2], aV[nt][g * 4 + 3]);
      }

    // ---- QK^T (swapped): weiT = K · Q^T ----
    f32x16 wei;
#pragma unroll
    for (int r = 0; r < 16; ++r) wei[r] = 0.0f;
#pragma unroll
    for (int kk = 0; kk < 4; ++kk) {
      const int nt = kk >> 1, g0 = (2 * kk) & 3, g1 = (2 * kk + 1) & 3;
      unsigned k0w, k1w, k2w, k3w, q0w, q1w, q2w, q3w;
      plswap(Kp[nt][g0][0], Kp[nt][g1][0], k0w, k2w);
      plswap(Kp[nt][g0][1], Kp[nt][g1][1], k1w, k3w);
      plswap(Qp[nt][g0][0], Qp[nt][g1][0], q0w, q2w);
      plswap(Qp[nt][g0][1], Qp[nt][g1][1], q1w, q3w);
      uint4v kw = { k0w, k1w, k2w, k3w };
      uint4v qw = { q0w, q1w, q2w, q3w };
      wei = __builtin_amdgcn_mfma_f32_32x32x16_bf16(
          __builtin_bit_cast(bf16x8, kw), __builtin_bit_cast(bf16x8, qw), wei, 0, 0, 0);
    }

    // ---- softmax over s for query t=lo (lane pairs l, l^32) ----
    float pv[16];
    float m = -3.0e38f;
#pragma unroll
    for (int r = 0; r < 16; ++r) {
      int s = (r & 3) + 8 * (r >> 2) + 4 * hi;
      float v = (s <= lo) ? wei[r] * 0.125f : -__builtin_inff();
      pv[r] = v;
      m = fmaxf(m, v);
    }
    m = fmaxf(m, __shfl_xor(m, 32));
    float sum = 0.0f;
#pragma unroll
    for (int r = 0; r < 16; ++r) {
      float e = __expf(pv[r] - m);
      pv[r] = e;
      sum += e;
    }
    sum += __shfl_xor(sum, 32);
    const float inv = 1.0f / sum;

    unsigned Pp[4][2];
#pragma unroll
    for (int g = 0; g < 4; ++g) {
      Pp[g][0] = pk2(pv[g * 4 + 0] * inv, pv[g * 4 + 1] * inv);
      Pp[g][1] = pk2(pv[g * 4 + 2] * inv, pv[g * 4 + 3] * inv);
    }

    // ---- out = P · V  (+ bv via acc init; softmax row-sum = 1) ----
    f32x16 o[2];
#pragma unroll
    for (int r = 0; r < 16; ++r) { o[0][r] = bv0; o[1][r] = bv1; }

#pragma unroll
    for (int kk = 0; kk < 2; ++kk) {
      const int g0 = 2 * kk, g1 = 2 * kk + 1;
      unsigned p0w, p1w, p2w, p3w;
      plswap(Pp[g0][0], Pp[g1][0], p0w, p2w);
      plswap(Pp[g0][1], Pp[g1][1], p1w, p3w);
      uint4v pw = { p0w, p1w, p2w, p3w };
      bf16x8 pa = __builtin_bit_cast(bf16x8, pw);
#pragma unroll
      for (int nt = 0; nt < 2; ++nt) {
        unsigned v0w, v1w, v2w, v3w;
        plswap(Vp[nt][g0][0], Vp[nt][g1][0], v0w, v2w);
        plswap(Vp[nt][g0][1], Vp[nt][g1][1], v1w, v3w);
        uint4v vw = { v0w, v1w, v2w, v3w };
        o[nt] = __builtin_amdgcn_mfma_f32_32x32x16_bf16(
            pa, __builtin_bit_cast(bf16x8, vw), o[nt], 0, 0, 0);
      }
    }

    // ---- stores (2x128B segments per instr) ----
    float* ob = ob0 + j * (TT * HEAD);
#pragma unroll
    for (int nt = 0; nt < 2; ++nt) {
      int h = nt * 32 + lo;
#pragma unroll
      for (int r = 0; r < 16; ++r) {
        int row = (r & 3) + 8 * (r >> 2) + 4 * hi;
        ob[row * HEAD + h] = o[nt][r];
      }
    }
  }
}

extern "C" void kernel_launch(void* const* d_in, const int* in_sizes, int n_in,
                              void* d_out, int out_size, void* d_ws, size_t ws_size,
                              hipStream_t stream) {
  const float* X  = (const float*)d_in[0];
  const float* Wq = (const float*)d_in[1];
  const float* bq = (const float*)d_in[2];
  const float* Wk = (const float*)d_in[3];
  const float* bv = (const float*)d_in[6];
  const float* Wv = (const float*)d_in[5];
  float* out = (float*)d_out;
  unsigned short* Wt = (unsigned short*)d_ws;  // 192*256 bf16 = 96 KB scratch

  const int B = in_sizes[0] / (TT * EMB);  // 8192

  prep_weights<<<192, 256, 0, stream>>>(Wq, Wk, Wv, Wt);
  attn_kernel<<<B / (4 * NI), 256, 0, stream>>>(X, Wt, bq, bv, out);
}